// Round 4
// baseline (42800.092 us; speedup 1.0000x reference)
//
#include <hip/hip_runtime.h>
#include <hip/hip_fp16.h>
#include <math.h>

// ---------------------------------------------------------------------------
// FARGAN core. B=128, T=504, nb_frames=500, steps=2000, SUB=40.
// Round 10: 2 BATCHES PER BLOCK. 64 blocks x 1024 threads.
// Rationale: rounds 7-9 proved the allocator pins VGPRs at 64 and spills all
// weight-residency attempts. The real bottleneck is per-block L2 weight
// streaming (~1.3 MB/step) which every block repeats for ONE batch. Here each
// weight uint4 is loaded once per block and dotted against BOTH batches'
// x-vectors (LDS broadcast reads are free) -> 2x arithmetic intensity per
// streamed byte, per-batch step cost ~halved.
// Thread mappings per phase are EXACTLY round-6's; per-batch summation order
// unchanged -> absmax must stay 0.001281738.
// LDS stash: fwcglu + glu2 + sig + gout (118.3 KB). Everything else streams.
// No VGPR-resident weights (falsified r7/r8/r9).
// ---------------------------------------------------------------------------

#define DEV __device__ __forceinline__

DEV float sigm(float x) { return 1.0f / (1.0f + __expf(-x)); }
DEV float tanh_f(float x) { return 1.0f - 2.0f / (__expf(2.0f * x) + 1.0f); }

typedef _Float16 h2v __attribute__((ext_vector_type(2)));

#if defined(__has_builtin)
#if __has_builtin(__builtin_amdgcn_fdot2)
#define HAVE_FDOT2 1
#endif
#endif

DEV float fdot2(h2v a, h2v b, float c) {
#ifdef HAVE_FDOT2
    return __builtin_amdgcn_fdot2(a, b, c, false);
#else
    return c + (float)a[0] * (float)b[0] + (float)a[1] * (float)b[1];
#endif
}

// ---- workspace layout (float offsets) ----
constexpr size_t STEPS = 2000;
constexpr size_t OFF_X     = 0;          // 128*502*64 f32
constexpr size_t OFF_Y     = 4200000;    // 128*500*128 f32
constexpr size_t OFF_GAIN  = 12392000;   // 128*2000 f32
constexpr size_t OFF_CONDH = 12648000;   // 128*500*320 halves
constexpr size_t OFF_W     = 22888000;   // fp16 weights

// packed fp16 weights: OUT*KPAD halves, layout uint4[(k/8)*OUT + j]
constexpr size_t W_FWC     = 0;                       // 192 x 352
constexpr size_t W_FWCGLU  = W_FWC    + 192*352;      // 192 x 192  (LDS)
constexpr size_t W_GOUT    = W_FWCGLU + 192*192;      // 4   x 192  (LDS)
constexpr size_t W_G1IH    = W_GOUT   + 4*192;        // 480 x 272
constexpr size_t W_G1HH    = W_G1IH   + 480*272;      // 480 x 160
constexpr size_t W_GLU1    = W_G1HH   + 480*160;      // 160 x 160
constexpr size_t W_G2IH    = W_GLU1   + 160*160;      // 384 x 240
constexpr size_t W_G2HH    = W_G2IH   + 384*240;      // 384 x 128
constexpr size_t W_GLU2    = W_G2HH   + 384*128;      // 128 x 128  (LDS)
constexpr size_t W_G3IH    = W_GLU2   + 128*128;      // 384 x 208
constexpr size_t W_G3HH    = W_G3IH   + 384*208;      // 384 x 128
constexpr size_t W_GLU3    = W_G3HH   + 384*128;      // 128 x 128
constexpr size_t W_SKIP    = W_GLU3   + 128*128;      // 128 x 704
constexpr size_t W_SKIPGLU = W_SKIP   + 128*704;      // 128 x 128
constexpr size_t W_SIG     = W_SKIPGLU+ 128*128;      // 40  x 128  (LDS)

// LDS weight stash offsets (uint4 units)
constexpr int WL_FWCGLU = 0;       // 24*192 = 4608
constexpr int WL_GLU2   = 4608;    // 16*128 = 2048
constexpr int WL_SIG    = 6656;    // 2*8*40 = 640
constexpr int WL_GOUT   = 7296;    // 24*4   = 96
constexpr int WL_TOT    = 7392;    // 118,272 B

// ---------------------------------------------------------------------------
__global__ void k_pack_h(const float* __restrict__ src, __half* __restrict__ dst,
                         int OUT, int K, int KP8) {
    int t = blockIdx.x * 256 + threadIdx.x;
    if (t >= OUT * KP8) return;
    int j = t % OUT;
    int k8 = t / OUT;
    __half* d = dst + (size_t)t * 8;
#pragma unroll
    for (int i = 0; i < 8; ++i) {
        int k = k8 * 8 + i;
        d[i] = (k < K) ? __float2half(src[(size_t)j * K + k]) : __float2half(0.0f);
    }
}

// ---------------------------------------------------------------------------
// frontend (unchanged — verified)
// ---------------------------------------------------------------------------
__global__ void k_feat(const float* __restrict__ features, const int* __restrict__ period,
                       const float* __restrict__ pembed, const float* __restrict__ fd1,
                       float* __restrict__ xbuf) {
    int t = blockIdx.x * 256 + threadIdx.x;
    const int total = 128 * 502 * 64;
    if (t >= total) return;
    int o = t & 63;
    int r = t >> 6;
    int ft = r % 502;
    int b = r / 502;
    const float* f = features + ((size_t)b * 504 + ft + 2) * 20;
    int per = period[b * 504 + ft + 2];
    per = min(max(per, 32), 254);
    const float* pe = pembed + (per - 32) * 12;
    const float* w = fd1 + o * 32;
    float acc = 0.0f;
#pragma unroll
    for (int i = 0; i < 20; ++i) acc += f[i] * w[i];
#pragma unroll
    for (int i = 0; i < 12; ++i) acc += pe[i] * w[20 + i];
    xbuf[t] = tanh_f(acc);
}

__global__ void k_conv(const float* __restrict__ xbuf, const float* __restrict__ fconv1,
                       float* __restrict__ ybuf) {
    int t = blockIdx.x * 256 + threadIdx.x;
    const int total = 128 * 500 * 128;
    if (t >= total) return;
    int oc = t & 127;
    int r = t >> 7;
    int tt = r % 500;
    int b = r / 500;
    const float* xp = xbuf + ((size_t)b * 502 + tt) * 64;
    const float* w = fconv1 + oc * 192;
    float acc = 0.0f;
#pragma unroll 8
    for (int i = 0; i < 64; ++i) {
        acc += xp[i] * w[i * 3 + 0];
        acc += xp[64 + i] * w[i * 3 + 1];
        acc += xp[128 + i] * w[i * 3 + 2];
    }
    ybuf[t] = tanh_f(acc);
}

__global__ void k_cond(const float* __restrict__ ybuf, const float* __restrict__ fd2,
                       __half* __restrict__ cond) {
    int b = blockIdx.x / 50;
    int t0 = (blockIdx.x % 50) * 10;
    int tid = threadIdx.x;
    __shared__ float yl[1280];
    for (int i = tid; i < 1280; i += 320)
        yl[i] = ybuf[((size_t)b * 500 + t0) * 128 + i];
    __syncthreads();
    const float* w = fd2 + tid * 128;
    float acc[10];
#pragma unroll
    for (int q = 0; q < 10; ++q) acc[q] = 0.0f;
#pragma unroll 4
    for (int k = 0; k < 128; ++k) {
        float wv = w[k];
#pragma unroll
        for (int q = 0; q < 10; ++q) acc[q] += wv * yl[q * 128 + k];
    }
#pragma unroll
    for (int q = 0; q < 10; ++q)
        cond[((size_t)b * 500 + t0 + q) * 320 + tid] = __float2half(tanh_f(acc[q]));
}

__global__ void k_gain(const __half* __restrict__ cond, const float* __restrict__ cgw,
                       const float* __restrict__ cgb, float* __restrict__ gains) {
    int t = blockIdx.x * 256 + threadIdx.x;
    const int total = 128 * 2000;
    if (t >= total) return;
    int s = t % 2000;
    int b = t / 2000;
    int frame = s >> 2, sub = s & 3;
    const __half* c = cond + ((size_t)b * 500 + frame) * 320 + sub * 80;
    float acc = 0.0f;
#pragma unroll 8
    for (int i = 0; i < 80; ++i) acc += __half2float(c[i]) * cgw[i];
    float g = 0.2f + 0.8f * sigm(acc + cgb[0]);
    g = fminf(20.0f, fmaxf(0.001f, g));
    gains[t] = g;
}

// ---------------------------------------------------------------------------
// dual-batch 8-wide fp16 dot: one weight uint4, two x-vectors
// ---------------------------------------------------------------------------
DEV void dot8h2(uint4 w, uint4 x0, uint4 x1,
                float& a0, float& a1, float& b0, float& b1) {
    const h2v* wv = (const h2v*)&w;
    const h2v* x0v = (const h2v*)&x0;
    const h2v* x1v = (const h2v*)&x1;
    a0 = fdot2(wv[0], x0v[0], a0);
    b0 = fdot2(wv[0], x1v[0], b0);
    a1 = fdot2(wv[1], x0v[1], a1);
    b1 = fdot2(wv[1], x1v[1], b1);
    a0 = fdot2(wv[2], x0v[2], a0);
    b0 = fdot2(wv[2], x1v[2], b0);
    a1 = fdot2(wv[3], x0v[3], a1);
    b1 = fdot2(wv[3], x1v[3], b1);
}

// dual-batch packed matvec partial (global weights)
template <int OUT, int KP8, int S>
DEV void mv2(const uint4* __restrict__ WT, const __half* x0, const __half* x1,
             float* p0, float* p1, int tid) {
    static_assert(KP8 % S == 0, "KP8 % S");
    constexpr int KS8 = KP8 / S;
    if (tid < OUT * S) {
        int j = tid % OUT;
        int sl = tid / OUT;
        const uint4* w = WT + (size_t)sl * KS8 * OUT + j;
        const uint4* xx0 = (const uint4*)x0 + (size_t)sl * KS8;
        const uint4* xx1 = (const uint4*)x1 + (size_t)sl * KS8;
        float a0 = 0.0f, a1 = 0.0f, b0 = 0.0f, b1 = 0.0f;
#pragma unroll 4
        for (int k = 0; k < KS8; ++k)
            dot8h2(w[(size_t)k * OUT], xx0[k], xx1[k], a0, a1, b0, b1);
        p0[tid] = a0 + a1;
        p1[tid] = b0 + b1;
    }
}

// dual-batch matvec, LDS-resident weights
template <int OUT, int KP8, int S>
DEV void mv2_l(const uint4* wl, const __half* x0, const __half* x1,
               float* p0, float* p1, int tid) {
    constexpr int KS8 = KP8 / S;
    if (tid < OUT * S) {
        int j = tid % OUT;
        int sl = tid / OUT;
        const uint4* w = wl + (size_t)sl * KS8 * OUT + j;
        const uint4* xx0 = (const uint4*)x0 + (size_t)sl * KS8;
        const uint4* xx1 = (const uint4*)x1 + (size_t)sl * KS8;
        float a0 = 0.0f, a1 = 0.0f, b0 = 0.0f, b1 = 0.0f;
#pragma unroll
        for (int k = 0; k < KS8; ++k)
            dot8h2(w[(size_t)k * OUT], xx0[k], xx1[k], a0, a1, b0, b1);
        p0[tid] = a0 + a1;
        p1[tid] = b0 + b1;
    }
}

// dual-batch GRU double partial (S=2), both matrices global
template <int OUT, int KP8A, int KP8B>
DEV void gru_p2(const uint4* __restrict__ wa, const __half* xa0, const __half* xa1,
                const uint4* __restrict__ wb, const __half* xb0, const __half* xb1,
                float* pa0, float* pa1, float* pb0, float* pb1, int tid) {
    static_assert((KP8A % 2 == 0) && (KP8B % 2 == 0), "even");
    constexpr int KA = KP8A / 2, KB = KP8B / 2;
    if (tid < OUT * 2) {
        int j = tid % OUT;
        int sl = tid / OUT;
        {
            const uint4* w = wa + (size_t)sl * KA * OUT + j;
            const uint4* x0 = (const uint4*)xa0 + (size_t)sl * KA;
            const uint4* x1 = (const uint4*)xa1 + (size_t)sl * KA;
            float a0 = 0.0f, a1 = 0.0f, b0 = 0.0f, b1 = 0.0f;
#pragma unroll 4
            for (int k = 0; k < KA; ++k)
                dot8h2(w[(size_t)k * OUT], x0[k], x1[k], a0, a1, b0, b1);
            pa0[tid] = a0 + a1;
            pa1[tid] = b0 + b1;
        }
        {
            const uint4* w = wb + (size_t)sl * KB * OUT + j;
            const uint4* x0 = (const uint4*)xb0 + (size_t)sl * KB;
            const uint4* x1 = (const uint4*)xb1 + (size_t)sl * KB;
            float a0 = 0.0f, a1 = 0.0f, b0 = 0.0f, b1 = 0.0f;
#pragma unroll 4
            for (int k = 0; k < KB; ++k)
                dot8h2(w[(size_t)k * OUT], x0[k], x1[k], a0, a1, b0, b1);
            pb0[tid] = a0 + a1;
            pb1[tid] = b0 + b1;
        }
    }
}

template <int H>
DEV void gru_update(const float* __restrict__ pa, const float* __restrict__ pb,
                    float* __restrict__ s, __half* __restrict__ sh, int tid) {
    constexpr int OUT = 3 * H;
    if (tid < H) {
        float gi_r = pa[tid] + pa[OUT + tid];
        float gh_r = pb[tid] + pb[OUT + tid];
        float gi_z = pa[H + tid] + pa[OUT + H + tid];
        float gh_z = pb[H + tid] + pb[OUT + H + tid];
        float gi_n = pa[2 * H + tid] + pa[OUT + 2 * H + tid];
        float gh_n = pb[2 * H + tid] + pb[OUT + 2 * H + tid];
        float r = sigm(gi_r + gh_r);
        float z = sigm(gi_z + gh_z);
        float n = tanh_f(gi_n + r * gh_n);
        float v = (1.0f - z) * n + z * s[tid];
        s[tid] = v;
        sh[tid] = __float2half(v);
    }
}

// ---------------------------------------------------------------------------
// main recurrent kernel: 64 blocks x 1024 threads, 2 batches per block
// ---------------------------------------------------------------------------
__global__ __launch_bounds__(1024) void fargan_main(const float* __restrict__ ws,
                                                    const int* __restrict__ period,
                                                    const float* __restrict__ goutb,
                                                    float* __restrict__ out) {
    const int bid = blockIdx.x;
    const int b0 = 2 * bid, b1 = 2 * bid + 1;
    const int tid = threadIdx.x;

    const __half* cond = (const __half*)(ws + OFF_CONDH);
    const float* gains = ws + OFF_GAIN;
    const __half* whb  = (const __half*)(ws + OFF_W);
    const uint4* wFWC     = (const uint4*)(whb + W_FWC);
    const uint4* wFWCGLU  = (const uint4*)(whb + W_FWCGLU);
    const uint4* wGOUT    = (const uint4*)(whb + W_GOUT);
    const uint4* wG1IH    = (const uint4*)(whb + W_G1IH);
    const uint4* wG1HH    = (const uint4*)(whb + W_G1HH);
    const uint4* wGLU1    = (const uint4*)(whb + W_GLU1);
    const uint4* wG2IH    = (const uint4*)(whb + W_G2IH);
    const uint4* wG2HH    = (const uint4*)(whb + W_G2HH);
    const uint4* wGLU2    = (const uint4*)(whb + W_GLU2);
    const uint4* wG3IH    = (const uint4*)(whb + W_G3IH);
    const uint4* wG3HH    = (const uint4*)(whb + W_G3HH);
    const uint4* wGLU3    = (const uint4*)(whb + W_GLU3);
    const uint4* wSKIP    = (const uint4*)(whb + W_SKIP);
    const uint4* wSKIPGLU = (const uint4*)(whb + W_SKIPGLU);
    const uint4* wSIG     = (const uint4*)(whb + W_SIG);

    // LDS weight stash (118.3 KB): fwcglu + glu2 + sig + gout
    __shared__ __align__(16) uint4 wlds[WL_TOT];

    // per-batch fp16 matvec inputs [2][...]
    __shared__ __align__(16) __half xcat_h[2][352];
    __shared__ __align__(16) __half inb_h[2][272];
    __shared__ __align__(16) __half fwcpre_h[2][192], fwcout_h[2][192];
    __shared__ __align__(16) __half s1_h[2][160], s2_h[2][128], s3_h[2][128];
    __shared__ __align__(16) __half g1_h[2][160], g2_h[2][128], g3_h[2][128];
    __shared__ __align__(16) __half skipin_h[2][704], skippre_h[2][128], skipout_h[2][128];
    // per-batch fp32 masters
    __shared__ __align__(16) float exc[2][256];
    __shared__ __align__(16) float s1[2][160], s2[2][128], s3[2][128];
    __shared__ __align__(16) float partA[2][1024], partB[2][1024];
    __shared__ __align__(16) float fwcpre[2][192];
    __shared__ __align__(16) float pg[2][4];
    __shared__ __align__(16) float skippre[2][128];
    __shared__ __align__(16) float sigraw[2][40];

    // stash LDS weights
    for (int i = tid; i < WL_TOT; i += 1024) {
        uint4 v;
        if (i < 4608)      v = wFWCGLU[i];
        else if (i < 6656) v = wGLU2[i - 4608];
        else if (i < 7296) v = wSIG[i - 6656];
        else               v = wGOUT[i - 7296];
        wlds[i] = v;
    }

    // zero-init state (both batches)
    for (int i = tid; i < 512; i += 1024) ((float*)exc)[i] = 0.0f;
    if (tid < 160) {
        s1[0][tid] = 0.0f; s1[1][tid] = 0.0f;
        s1_h[0][tid] = __float2half(0.0f); s1_h[1][tid] = __float2half(0.0f);
    }
    if (tid < 128) {
        s2[0][tid] = 0.0f; s2[1][tid] = 0.0f;
        s3[0][tid] = 0.0f; s3[1][tid] = 0.0f;
        s2_h[0][tid] = __float2half(0.0f); s2_h[1][tid] = __float2half(0.0f);
        s3_h[0][tid] = __float2half(0.0f); s3_h[1][tid] = __float2half(0.0f);
    }
    if (tid < 164) {
        xcat_h[0][tid] = __float2half(0.0f);
        xcat_h[1][tid] = __float2half(0.0f);
    }
    if (tid >= 328 && tid < 352) {
        xcat_h[0][tid] = __float2half(0.0f);
        xcat_h[1][tid] = __float2half(0.0f);
    }
    if (tid >= 688 && tid < 704) {
        skipin_h[0][tid] = __float2half(0.0f);
        skipin_h[1][tid] = __float2half(0.0f);
    }
    __syncthreads();

    for (int s = 0; s < (int)STEPS; ++s) {
        const int frame = s >> 2;
        const float gn0 = gains[(size_t)b0 * 2000 + s];
        const float gn1 = gains[(size_t)b1 * 2000 + s];
        const float ig0 = 1.0f / (1e-5f + gn0);
        const float ig1 = 1.0f / (1e-5f + gn1);
        int per0 = min(max(period[b0 * 504 + 3 + frame], 32), 254);
        int per1 = min(max(period[b1 * 504 + 3 + frame], 32), 254);

        // Phase A: gather cond80, pred, prev into xcat_h (both batches)
        if (tid < 80) {
            xcat_h[0][164 + tid] = cond[((size_t)b0 * 500 + frame) * 320 + (s & 3) * 80 + tid];
            xcat_h[1][164 + tid] = cond[((size_t)b1 * 500 + frame) * 320 + (s & 3) * 80 + tid];
        } else if (tid >= 128 && tid < 172) {
            int j = tid - 128;
            {
                int idx = 254 - per0 + j;
                if (idx >= 256) idx -= per0;
                idx = min(255, max(0, idx));
                xcat_h[0][244 + j] = __float2half(exc[0][idx] * ig0);
            }
            {
                int idx = 254 - per1 + j;
                if (idx >= 256) idx -= per1;
                idx = min(255, max(0, idx));
                xcat_h[1][244 + j] = __float2half(exc[1][idx] * ig1);
            }
        } else if (tid >= 192 && tid < 232) {
            int j = tid - 192;
            xcat_h[0][288 + j] = __float2half(exc[0][216 + j] * ig0);
            xcat_h[1][288 + j] = __float2half(exc[1][216 + j] * ig1);
        }
        __syncthreads();

        // Phase B: fwc partial (OUT=192, KP8=44, S=4)
        mv2<192, 44, 4>(wFWC, xcat_h[0], xcat_h[1], partA[0], partA[1], tid);
        __syncthreads();
        // Phase C: reduce -> fwcpre
        if (tid < 192) {
#pragma unroll
            for (int g = 0; g < 2; ++g) {
                float a = partA[g][tid] + partA[g][192 + tid] + partA[g][384 + tid] + partA[g][576 + tid];
                float t = tanh_f(a);
                fwcpre[g][tid] = t;
                fwcpre_h[g][tid] = __float2half(t);
            }
        }
        __syncthreads();

        // Phase D: fwcglu (LDS) || gout (LDS) || xcat shift
        mv2_l<192, 24, 4>(wlds + WL_FWCGLU, fwcpre_h[0], fwcpre_h[1], partA[0], partA[1], tid);
        if (tid >= 768 && tid < 800) {
            int t2 = tid - 768;
            int j = t2 & 3, sl = t2 >> 2;
            const uint4* w = wlds + WL_GOUT + (sl * 3) * 4 + j;
            const uint4* xx0 = (const uint4*)fwcpre_h[0] + sl * 3;
            const uint4* xx1 = (const uint4*)fwcpre_h[1] + sl * 3;
            float a0 = 0.0f, a1 = 0.0f, c0 = 0.0f, c1 = 0.0f;
#pragma unroll
            for (int k = 0; k < 3; ++k) dot8h2(w[k * 4], xx0[k], xx1[k], a0, a1, c0, c1);
            partB[0][t2] = a0 + a1;
            partB[1][t2] = c0 + c1;
        } else if (tid >= 832 && tid < 996) {
            xcat_h[0][tid - 832] = xcat_h[0][tid - 832 + 164];
            xcat_h[1][tid - 832] = xcat_h[1][tid - 832 + 164];
        }
        __syncthreads();

        // Phase E: fwcout + pg + inb(gru1)
        if (tid < 192) {
#pragma unroll
            for (int g = 0; g < 2; ++g) {
                float a = partA[g][tid] + partA[g][192 + tid] + partA[g][384 + tid] + partA[g][576 + tid];
                float v = fwcpre[g][tid] * sigm(a);
                __half vh = __float2half(v);
                fwcout_h[g][tid] = vh;
                inb_h[g][tid] = vh;
            }
        } else if (tid < 232) {
#pragma unroll
            for (int g = 0; g < 2; ++g) {
                float a = goutb[0];
#pragma unroll
                for (int sl = 0; sl < 8; ++sl) a += partB[g][sl * 4];
                inb_h[g][tid] = __float2half(sigm(a) * __half2float(xcat_h[g][246 + tid - 192]));
            }
        } else if (tid < 272) {
            inb_h[0][tid] = xcat_h[0][288 + tid - 232];
            inb_h[1][tid] = xcat_h[1][288 + tid - 232];
        } else if (tid >= 960 && tid < 964) {
            int j = tid - 960;
#pragma unroll
            for (int g = 0; g < 2; ++g) {
                float a = goutb[j];
#pragma unroll
                for (int sl = 0; sl < 8; ++sl) a += partB[g][sl * 4 + j];
                pg[g][j] = sigm(a);
            }
        }
        __syncthreads();

        // Phase F/G: GRU1 (H=160, OUT=480; KP8 34/20)
        gru_p2<480, 34, 20>(wG1IH, inb_h[0], inb_h[1], wG1HH, s1_h[0], s1_h[1],
                            partA[0], partA[1], partB[0], partB[1], tid);
        __syncthreads();
        gru_update<160>(partA[0], partB[0], s1[0], s1_h[0], tid);
        gru_update<160>(partA[1], partB[1], s1[1], s1_h[1], tid);
        __syncthreads();

        // Phase H/I: GLU1 (160x160, KP8=20, S=4) + inb(gru2) build
        mv2<160, 20, 4>(wGLU1, s1_h[0], s1_h[1], partA[0], partA[1], tid);
        __syncthreads();
        if (tid < 160) {
#pragma unroll
            for (int g = 0; g < 2; ++g) {
                float a = partA[g][tid] + partA[g][160 + tid] + partA[g][320 + tid] + partA[g][480 + tid];
                float v = s1[g][tid] * sigm(a);
                __half vh = __float2half(v);
                g1_h[g][tid] = vh;
                inb_h[g][tid] = vh;
            }
        } else if (tid < 200) {
            inb_h[0][tid] = __float2half(pg[0][1] * __half2float(xcat_h[0][246 + tid - 160]));
            inb_h[1][tid] = __float2half(pg[1][1] * __half2float(xcat_h[1][246 + tid - 160]));
        } else if (tid < 240) {
            inb_h[0][tid] = xcat_h[0][288 + tid - 200];
            inb_h[1][tid] = xcat_h[1][288 + tid - 200];
        }
        __syncthreads();

        // Phase J/K: GRU2 (H=128, OUT=384; KP8 30/16)
        gru_p2<384, 30, 16>(wG2IH, inb_h[0], inb_h[1], wG2HH, s2_h[0], s2_h[1],
                            partA[0], partA[1], partB[0], partB[1], tid);
        __syncthreads();
        gru_update<128>(partA[0], partB[0], s2[0], s2_h[0], tid);
        gru_update<128>(partA[1], partB[1], s2[1], s2_h[1], tid);
        __syncthreads();

        // Phase L/M: GLU2 (LDS weights, 128x128, S=8) + inb(gru3) build
        mv2_l<128, 16, 8>(wlds + WL_GLU2, s2_h[0], s2_h[1], partA[0], partA[1], tid);
        __syncthreads();
        if (tid < 128) {
#pragma unroll
            for (int g = 0; g < 2; ++g) {
                float a = 0.0f;
#pragma unroll
                for (int sl = 0; sl < 8; ++sl) a += partA[g][sl * 128 + tid];
                float v = s2[g][tid] * sigm(a);
                __half vh = __float2half(v);
                g2_h[g][tid] = vh;
                inb_h[g][tid] = vh;
            }
        } else if (tid < 168) {
            inb_h[0][tid] = __float2half(pg[0][2] * __half2float(xcat_h[0][246 + tid - 128]));
            inb_h[1][tid] = __float2half(pg[1][2] * __half2float(xcat_h[1][246 + tid - 128]));
        } else if (tid < 208) {
            inb_h[0][tid] = xcat_h[0][288 + tid - 168];
            inb_h[1][tid] = xcat_h[1][288 + tid - 168];
        }
        __syncthreads();

        // Phase N/O: GRU3 (H=128, OUT=384; KP8 26/16)
        gru_p2<384, 26, 16>(wG3IH, inb_h[0], inb_h[1], wG3HH, s3_h[0], s3_h[1],
                            partA[0], partA[1], partB[0], partB[1], tid);
        __syncthreads();
        gru_update<128>(partA[0], partB[0], s3[0], s3_h[0], tid);
        gru_update<128>(partA[1], partB[1], s3[1], s3_h[1], tid);
        __syncthreads();

        // Phase P/Q: GLU3 (streamed, 128x128, S=8) + skipin build
        mv2<128, 16, 8>(wGLU3, s3_h[0], s3_h[1], partA[0], partA[1], tid);
        __syncthreads();
        if (tid < 128) {
#pragma unroll
            for (int g = 0; g < 2; ++g) {
                float a = 0.0f;
#pragma unroll
                for (int sl = 0; sl < 8; ++sl) a += partA[g][sl * 128 + tid];
                float v = s3[g][tid] * sigm(a);
                __half vh = __float2half(v);
                g3_h[g][tid] = vh;
                skipin_h[g][288 + tid] = vh;
            }
        } else if (tid < 288) {
            skipin_h[0][tid - 128] = g1_h[0][tid - 128];
            skipin_h[1][tid - 128] = g1_h[1][tid - 128];
        } else if (tid < 416) {
            skipin_h[0][160 + tid - 288] = g2_h[0][tid - 288];
            skipin_h[1][160 + tid - 288] = g2_h[1][tid - 288];
        } else if (tid < 608) {
            skipin_h[0][tid] = fwcout_h[0][tid - 416];
            skipin_h[1][tid] = fwcout_h[1][tid - 416];
        } else if (tid < 648) {
            skipin_h[0][tid] = __float2half(pg[0][3] * __half2float(xcat_h[0][246 + tid - 608]));
            skipin_h[1][tid] = __float2half(pg[1][3] * __half2float(xcat_h[1][246 + tid - 608]));
        } else if (tid < 688) {
            skipin_h[0][tid] = xcat_h[0][288 + tid - 648];
            skipin_h[1][tid] = xcat_h[1][288 + tid - 648];
        }
        __syncthreads();

        // Phase R/S: skip (128x688, KP8=88, S=8)
        mv2<128, 88, 8>(wSKIP, skipin_h[0], skipin_h[1], partA[0], partA[1], tid);
        __syncthreads();
        if (tid < 128) {
#pragma unroll
            for (int g = 0; g < 2; ++g) {
                float a = 0.0f;
#pragma unroll
                for (int sl = 0; sl < 8; ++sl) a += partA[g][sl * 128 + tid];
                float t = tanh_f(a);
                skippre[g][tid] = t;
                skippre_h[g][tid] = __float2half(t);
            }
        }
        __syncthreads();

        // Phase T/U: skipglu (128x128, S=8)
        mv2<128, 16, 8>(wSKIPGLU, skippre_h[0], skippre_h[1], partA[0], partA[1], tid);
        __syncthreads();
        if (tid < 128) {
#pragma unroll
            for (int g = 0; g < 2; ++g) {
                float a = 0.0f;
#pragma unroll
                for (int sl = 0; sl < 8; ++sl) a += partA[g][sl * 128 + tid];
                skipout_h[g][tid] = __float2half(skippre[g][tid] * sigm(a));
            }
        }
        __syncthreads();

        // Phase V: sig partial (LDS weights, 40x128, KP8=16, S=8)
        mv2_l<40, 16, 8>(wlds + WL_SIG, skipout_h[0], skipout_h[1], partA[0], partA[1], tid);
        __syncthreads();
        // Phase W: sig reduce + read old exc
        float keep0 = (tid < 216) ? exc[0][tid + 40] : 0.0f;
        float keep1 = (tid < 216) ? exc[1][tid + 40] : 0.0f;
        if (tid < 40) {
#pragma unroll
            for (int g = 0; g < 2; ++g) {
                float a = 0.0f;
#pragma unroll
                for (int sl = 0; sl < 8; ++sl) a += partA[g][sl * 40 + tid];
                sigraw[g][tid] = tanh_f(a) * (g == 0 ? gn0 : gn1);
            }
        }
        __syncthreads();
        // Phase X: exc shift + output
        if (tid < 216) {
            exc[0][tid] = keep0;
            exc[1][tid] = keep1;
        } else if (tid < 256) {
            float sv0 = sigraw[0][tid - 216];
            float sv1 = sigraw[1][tid - 216];
            exc[0][tid] = sv0;
            exc[1][tid] = sv1;
            out[(size_t)b0 * 80000 + (size_t)s * 40 + (tid - 216)] = sv0;
            out[(size_t)b1 * 80000 + (size_t)s * 40 + (tid - 216)] = sv1;
        }
        __syncthreads();
    }
}

// ---------------------------------------------------------------------------
extern "C" void kernel_launch(void* const* d_in, const int* in_sizes, int n_in,
                              void* d_out, int out_size, void* d_ws, size_t ws_size,
                              hipStream_t stream) {
    const float* features = (const float*)d_in[0];
    const int*   period   = (const int*)d_in[1];
    const float* pembed   = (const float*)d_in[2];
    const float* fd1_w    = (const float*)d_in[3];
    const float* fconv1_w = (const float*)d_in[4];
    const float* fd2_w    = (const float*)d_in[5];
    const float* cg_w     = (const float*)d_in[6];
    const float* cg_b     = (const float*)d_in[7];
    const float* fwc_w    = (const float*)d_in[8];
    const float* fwc_glu  = (const float*)d_in[9];
    const float* g1_ih    = (const float*)d_in[10];
    const float* g1_hh    = (const float*)d_in[11];
    const float* glu1_w   = (const float*)d_in[12];
    const float* g2_ih    = (const float*)d_in[13];
    const float* g2_hh    = (const float*)d_in[14];
    const float* glu2_w   = (const float*)d_in[15];
    const float* g3_ih    = (const float*)d_in[16];
    const float* g3_hh    = (const float*)d_in[17];
    const float* glu3_w   = (const float*)d_in[18];
    const float* skip_w   = (const float*)d_in[19];
    const float* skip_glu = (const float*)d_in[20];
    const float* sig_w    = (const float*)d_in[21];
    const float* gout_w   = (const float*)d_in[22];
    const float* gout_b   = (const float*)d_in[23];

    float* ws = (float*)d_ws;
    float* out = (float*)d_out;
    __half* wh = (__half*)(ws + OFF_W);

    struct PW { const float* src; size_t off; int out, k, kpad; };
    const PW pws[15] = {
        {fwc_w,    W_FWC,     192, 328, 352}, {fwc_glu, W_FWCGLU, 192, 192, 192},
        {gout_w,   W_GOUT,      4, 192, 192}, {g1_ih,   W_G1IH,   480, 272, 272},
        {g1_hh,    W_G1HH,    480, 160, 160}, {glu1_w,  W_GLU1,   160, 160, 160},
        {g2_ih,    W_G2IH,    384, 240, 240}, {g2_hh,   W_G2HH,   384, 128, 128},
        {glu2_w,   W_GLU2,    128, 128, 128}, {g3_ih,   W_G3IH,   384, 208, 208},
        {g3_hh,    W_G3HH,    384, 128, 128}, {glu3_w,  W_GLU3,   128, 128, 128},
        {skip_w,   W_SKIP,    128, 688, 704}, {skip_glu,W_SKIPGLU,128, 128, 128},
        {sig_w,    W_SIG,      40, 128, 128},
    };
    for (int i = 0; i < 15; ++i) {
        int kp8 = pws[i].kpad / 8;
        int n = pws[i].out * kp8;
        k_pack_h<<<(n + 255) / 256, 256, 0, stream>>>(pws[i].src, wh + pws[i].off,
                                                      pws[i].out, pws[i].k, kp8);
    }

    {
        int n = 128 * 502 * 64;
        k_feat<<<(n + 255) / 256, 256, 0, stream>>>(features, period, pembed, fd1_w,
                                                    ws + OFF_X);
    }
    {
        int n = 128 * 500 * 128;
        k_conv<<<(n + 255) / 256, 256, 0, stream>>>(ws + OFF_X, fconv1_w, ws + OFF_Y);
    }
    k_cond<<<128 * 50, 320, 0, stream>>>(ws + OFF_Y, fd2_w, (__half*)(ws + OFF_CONDH));
    {
        int n = 128 * 2000;
        k_gain<<<(n + 255) / 256, 256, 0, stream>>>((const __half*)(ws + OFF_CONDH),
                                                    cg_w, cg_b, ws + OFF_GAIN);
    }

    fargan_main<<<64, 1024, 0, stream>>>(ws, period, gout_b, out);
}